// Round 1
// baseline (314.116 us; speedup 1.0000x reference)
//
#include <hip/hip_runtime.h>
#include <math.h>

// Problem constants (from reference)
#define BB    2
#define TT    64
#define NN    128
#define TN    8192      // TT*NN
#define MM    16384     // BB*TN
#define CMAP  2048
#define CCOMP 32
#define FHW   256       // 16*16

// comp kernel split
#define CSPLIT 32
#define CRANGE 64       // CMAP / CSPLIT

// attention tiling
#define KC     128      // k rows staged in LDS per chunk
#define KSPLIT 16       // k-dimension split across blocks

// workspace layout (float offsets)
#define OFF_O    0                          // MM*8 accumulator
#define OFF_COMP (MM*8)                     // BB*FHW*CCOMP
#define OFF_Q    (OFF_COMP + BB*FHW*CCOMP)
#define OFF_K    (OFF_Q + MM*8)
#define OFF_V    (OFF_K + MM*8)
// total floats = 540672  (~2.1 MB) -- well under typical ws_size

__device__ __forceinline__ float sigmoidf_(float v) {
    return 1.0f / (1.0f + __expf(-v));
}

// K1: comp[b,o,h,w] = sum_c metadata[b,c,h,w]*comp_w[o,c] + comp_b[o]
// stored channel-innermost: comp_ws[((b*256+hw)*32)+o]
// grid (BB, CSPLIT), block 256 (one thread per hw). Channel-split partials
// combined with atomicAdd (comp_ws pre-zeroed by memset).
__global__ void k_comp(const float* __restrict__ metadata,
                       const float* __restrict__ comp_w,
                       const float* __restrict__ comp_b,
                       float* __restrict__ comp_ws) {
    const int b  = blockIdx.x;
    const int cs = blockIdx.y;
    const int hw = threadIdx.x;

    __shared__ float wcs[CRANGE][CCOMP];   // [c][o]
    for (int i = threadIdx.x; i < CRANGE * CCOMP; i += 256) {
        int c = i / CCOMP, o = i % CCOMP;
        wcs[c][o] = comp_w[o * CMAP + cs * CRANGE + c];
    }
    __syncthreads();

    float acc[CCOMP];
#pragma unroll
    for (int o = 0; o < CCOMP; o++) acc[o] = 0.0f;

    const float* mb = metadata + ((size_t)b * CMAP + (size_t)cs * CRANGE) * FHW + hw;
#pragma unroll 4
    for (int c = 0; c < CRANGE; c++) {
        float m = mb[c * FHW];
#pragma unroll
        for (int o = 0; o < CCOMP; o++) acc[o] += m * wcs[c][o];
    }

    float* outp = comp_ws + ((size_t)b * FHW + hw) * CCOMP;
    const float bs = (cs == 0) ? 1.0f : 0.0f;
#pragma unroll
    for (int o = 0; o < CCOMP; o++) {
        atomicAdd(&outp[o], acc[o] + bs * comp_b[o]);
    }
}

// K2: per-token: PE + LSTM + bilinear sample + vf + Q/K/V
__global__ void k_token(const float* __restrict__ x,
                        const float* __restrict__ w_ih,
                        const float* __restrict__ b_ih,
                        const float* __restrict__ b_hh,
                        const float* __restrict__ fc_w,  const float* __restrict__ fc_b,
                        const float* __restrict__ fc2_w, const float* __restrict__ fc2_b,
                        const float* __restrict__ fc3_w, const float* __restrict__ fc3_b,
                        const float* __restrict__ vf_w,  const float* __restrict__ vf_b,
                        const float* __restrict__ comp_ws,
                        float* __restrict__ Qw, float* __restrict__ Kw, float* __restrict__ Vw) {
    const int m = blockIdx.x * 256 + threadIdx.x;
    const int b = m >> 13;          // / TN
    const int p = m & (TN - 1);
    const int t = p >> 7;           // / NN

    const float px = x[(size_t)(b * 2 + 0) * TN + p];
    const float py = x[(size_t)(b * 2 + 1) * TN + p];

    // positional encoding (c=2 -> div=1): (sin t, cos t)
    const float xr0 = px + sinf((float)t);
    const float xr1 = py + cosf((float)t);

    // single-step LSTM, h0=c0=0: gates = xr @ w_ih.T + b_ih + b_hh
    float X[4];
#pragma unroll
    for (int j = 0; j < 4; j++) {
        float gi = xr0 * w_ih[(j)      * 2] + xr1 * w_ih[(j)      * 2 + 1] + b_ih[j]      + b_hh[j];
        float gg = xr0 * w_ih[(8 + j)  * 2] + xr1 * w_ih[(8 + j)  * 2 + 1] + b_ih[8 + j]  + b_hh[8 + j];
        float go = xr0 * w_ih[(12 + j) * 2] + xr1 * w_ih[(12 + j) * 2 + 1] + b_ih[12 + j] + b_hh[12 + j];
        float cst = sigmoidf_(gi) * tanhf(gg);
        X[j] = sigmoidf_(go) * tanhf(cst);
    }

    // bilinear grid-sample of comp (zeros padding, align_corners=False)
    // ix = px/32 - 0.5, iy = py/32 - 0.5
    float lc[CCOMP];
#pragma unroll
    for (int c = 0; c < CCOMP; c++) lc[c] = 0.0f;

    const float ix = px * (1.0f / 32.0f) - 0.5f;
    const float iy = py * (1.0f / 32.0f) - 0.5f;
    const float fx0 = floorf(ix), fy0 = floorf(iy);
    const float wx = ix - fx0, wy = iy - fy0;
    const int x0 = (int)fx0, y0 = (int)fy0;
    const float* cb = comp_ws + (size_t)b * FHW * CCOMP;

#pragma unroll
    for (int dy = 0; dy < 2; dy++) {
#pragma unroll
        for (int dx = 0; dx < 2; dx++) {
            int xx = x0 + dx, yy = y0 + dy;
            if (xx < 0 || xx > 15 || yy < 0 || yy > 15) continue;
            float w = (dy ? wy : 1.0f - wy) * (dx ? wx : 1.0f - wx);
            const float* cp = cb + (yy * 16 + xx) * CCOMP;
#pragma unroll
            for (int c = 0; c < CCOMP; c++) lc[c] += w * cp[c];
        }
    }

    // vf: X2 = [X(4), lc(32)] @ vf_w.T + vf_b   (vf_w: [4,36])
    float X2[4];
#pragma unroll
    for (int j = 0; j < 4; j++) {
        float a = vf_b[j];
#pragma unroll
        for (int k = 0; k < 4; k++) a += X[k] * vf_w[j * 36 + k];
#pragma unroll
        for (int c = 0; c < CCOMP; c++) a += lc[c] * vf_w[j * 36 + 4 + c];
        X2[j] = a;
    }

    // Q from X2 (fc_w [8,4]); K,V from xr (fc2_w/fc3_w [8,2])
#pragma unroll
    for (int d = 0; d < 8; d++) {
        float q = fc_b[d];
#pragma unroll
        for (int k = 0; k < 4; k++) q += X2[k] * fc_w[d * 4 + k];
        Qw[(size_t)m * 8 + d] = q;
        Kw[(size_t)m * 8 + d] = fc2_b[d] + xr0 * fc2_w[d * 2] + xr1 * fc2_w[d * 2 + 1];
        Vw[(size_t)m * 8 + d] = fc3_b[d] + xr0 * fc3_w[d * 2] + xr1 * fc3_w[d * 2 + 1];
    }
}

// K3: out[q,:] += sum_{k in split} sigmoid(Q_q . K_k) * V_k
// grid (BB*16, KSPLIT): each block = 512 q rows (2 per thread), 512 k rows.
__global__ void __launch_bounds__(256) k_attn(const float* __restrict__ Qw,
                                              const float* __restrict__ Kw,
                                              const float* __restrict__ Vw,
                                              float* __restrict__ Ow) {
    __shared__ float sK[KC][8];
    __shared__ float sV[KC][8];

    const int tile = blockIdx.x;       // 0..31
    const int b  = tile >> 4;
    const int tq = tile & 15;
    const int ks = blockIdx.y;

    const int q0 = b * TN + tq * 512 + threadIdx.x;
    const int q1 = q0 + 256;

    float Q0[8], Q1[8], a0[8], a1[8];
#pragma unroll
    for (int d = 0; d < 8; d++) {
        Q0[d] = Qw[(size_t)q0 * 8 + d];
        Q1[d] = Qw[(size_t)q1 * 8 + d];
        a0[d] = 0.0f;
        a1[d] = 0.0f;
    }

    const int kbase = b * TN + ks * (TN / KSPLIT);
    for (int ch = 0; ch < TN / KSPLIT; ch += KC) {
        // cooperative stage of KC rows of K and V (KC*8 = 1024 floats each)
        ((float4*)&sK[0][0])[threadIdx.x] =
            ((const float4*)(Kw + (size_t)(kbase + ch) * 8))[threadIdx.x];
        ((float4*)&sV[0][0])[threadIdx.x] =
            ((const float4*)(Vw + (size_t)(kbase + ch) * 8))[threadIdx.x];
        __syncthreads();

        for (int j = 0; j < KC; j++) {
            const float4* kj = (const float4*)&sK[j][0];
            float4 ka = kj[0], kb = kj[1];
            float d0 = Q0[0] * ka.x + Q0[1] * ka.y + Q0[2] * ka.z + Q0[3] * ka.w
                     + Q0[4] * kb.x + Q0[5] * kb.y + Q0[6] * kb.z + Q0[7] * kb.w;
            float d1 = Q1[0] * ka.x + Q1[1] * ka.y + Q1[2] * ka.z + Q1[3] * ka.w
                     + Q1[4] * kb.x + Q1[5] * kb.y + Q1[6] * kb.z + Q1[7] * kb.w;
            float p0 = 1.0f / (1.0f + __expf(-d0));
            float p1 = 1.0f / (1.0f + __expf(-d1));
            const float4* vj = (const float4*)&sV[j][0];
            float4 va = vj[0], vb = vj[1];
            a0[0] += p0 * va.x; a0[1] += p0 * va.y; a0[2] += p0 * va.z; a0[3] += p0 * va.w;
            a0[4] += p0 * vb.x; a0[5] += p0 * vb.y; a0[6] += p0 * vb.z; a0[7] += p0 * vb.w;
            a1[0] += p1 * va.x; a1[1] += p1 * va.y; a1[2] += p1 * va.z; a1[3] += p1 * va.w;
            a1[4] += p1 * vb.x; a1[5] += p1 * vb.y; a1[6] += p1 * vb.z; a1[7] += p1 * vb.w;
        }
        __syncthreads();
    }

#pragma unroll
    for (int d = 0; d < 8; d++) {
        atomicAdd(&Ow[(size_t)q0 * 8 + d], a0[d]);
        atomicAdd(&Ow[(size_t)q1 * 8 + d], a1[d]);
    }
}

// K4: threshold-ReLU + fcout + transpose to [B,2,T,N]
__global__ void k_out(const float* __restrict__ Ow,
                      const float* __restrict__ fcout_w,
                      const float* __restrict__ fcout_b,
                      float* __restrict__ y) {
    const int m = blockIdx.x * 256 + threadIdx.x;
    const int b = m >> 13;
    const int p = m & (TN - 1);

    float f0 = fcout_b[0], f1 = fcout_b[1];
#pragma unroll
    for (int d = 0; d < 8; d++) {
        float v = Ow[(size_t)m * 8 + d];
        v = (v > 0.5f) ? v : 0.0f;
        f0 += v * fcout_w[d];
        f1 += v * fcout_w[8 + d];
    }
    y[(size_t)(b * 2 + 0) * TN + p] = f0;
    y[(size_t)(b * 2 + 1) * TN + p] = f1;
}

extern "C" void kernel_launch(void* const* d_in, const int* in_sizes, int n_in,
                              void* d_out, int out_size, void* d_ws, size_t ws_size,
                              hipStream_t stream) {
    const float* x        = (const float*)d_in[0];
    const float* metadata = (const float*)d_in[1];
    const float* w_ih     = (const float*)d_in[2];
    // d_in[3] = w_hh: unused (h0 = 0)
    const float* b_ih     = (const float*)d_in[4];
    const float* b_hh     = (const float*)d_in[5];
    const float* fc_w     = (const float*)d_in[6];
    const float* fc_b     = (const float*)d_in[7];
    const float* fc2_w    = (const float*)d_in[8];
    const float* fc2_b    = (const float*)d_in[9];
    const float* fc3_w    = (const float*)d_in[10];
    const float* fc3_b    = (const float*)d_in[11];
    const float* comp_w   = (const float*)d_in[12];
    const float* comp_b   = (const float*)d_in[13];
    const float* vf_w     = (const float*)d_in[14];
    const float* vf_b     = (const float*)d_in[15];
    const float* fcout_w  = (const float*)d_in[16];
    const float* fcout_b  = (const float*)d_in[17];

    float* ws      = (float*)d_ws;
    float* Ow      = ws + OFF_O;
    float* comp_ws = ws + OFF_COMP;
    float* Qw      = ws + OFF_Q;
    float* Kw      = ws + OFF_K;
    float* Vw      = ws + OFF_V;

    // zero the atomic accumulators (O and comp regions are contiguous)
    hipMemsetAsync(ws, 0, (size_t)(MM * 8 + BB * FHW * CCOMP) * sizeof(float), stream);

    k_comp<<<dim3(BB, CSPLIT), 256, 0, stream>>>(metadata, comp_w, comp_b, comp_ws);

    k_token<<<MM / 256, 256, 0, stream>>>(x, w_ih, b_ih, b_hh,
                                          fc_w, fc_b, fc2_w, fc2_b, fc3_w, fc3_b,
                                          vf_w, vf_b, comp_ws, Qw, Kw, Vw);

    k_attn<<<dim3(BB * 16, KSPLIT), 256, 0, stream>>>(Qw, Kw, Vw, Ow);

    k_out<<<MM / 256, 256, 0, stream>>>(Ow, fcout_w, fcout_b, (float*)d_out);
}

// Round 2
// 289.683 us; speedup vs baseline: 1.0843x; 1.0843x over previous
//
#include <hip/hip_runtime.h>
#include <math.h>

// Problem constants (from reference)
#define BB    2
#define TT    64
#define NN    128
#define TN    8192      // TT*NN
#define MM    16384     // BB*TN
#define CMAP  2048
#define CCOMP 32
#define FHW   256       // 16*16

// comp kernel split
#define CSPLIT 32
#define CRANGE 64       // CMAP / CSPLIT

// attention tiling
#define KC     128      // k rows staged in LDS per chunk
#define KSPLIT 32       // k-dimension split across blocks (k-range 256/block)

// workspace layout (float offsets)
#define OFF_O    0                          // MM*8 accumulator
#define OFF_COMP (MM*8)                     // BB*FHW*CCOMP
#define OFF_Q    (OFF_COMP + BB*FHW*CCOMP)
#define OFF_K    (OFF_Q + MM*8)
#define OFF_V    (OFF_K + MM*8)

__device__ __forceinline__ float fast_sigmoid(float v) {
    // v_mul(-log2e folded by __expf) + v_exp + v_add + v_rcp  (~12 cyc)
    return __builtin_amdgcn_rcpf(1.0f + __expf(-v));
}

__device__ __forceinline__ float fast_tanh(float v) {
    // tanh(x) = 1 - 2/(1+e^{2x}); robust at |x| large (e^inf -> rcp -> 0)
    return 1.0f - 2.0f * __builtin_amdgcn_rcpf(1.0f + __expf(2.0f * v));
}

// K1: comp[b,o,h,w] = sum_c metadata[b,c,h,w]*comp_w[o,c] + comp_b[o]
// stored channel-innermost: comp_ws[((b*256+hw)*32)+o]
__global__ void k_comp(const float* __restrict__ metadata,
                       const float* __restrict__ comp_w,
                       const float* __restrict__ comp_b,
                       float* __restrict__ comp_ws) {
    const int b  = blockIdx.x;
    const int cs = blockIdx.y;
    const int hw = threadIdx.x;

    __shared__ float wcs[CRANGE][CCOMP];   // [c][o]
    for (int i = threadIdx.x; i < CRANGE * CCOMP; i += 256) {
        int c = i / CCOMP, o = i % CCOMP;
        wcs[c][o] = comp_w[o * CMAP + cs * CRANGE + c];
    }
    __syncthreads();

    float acc[CCOMP];
#pragma unroll
    for (int o = 0; o < CCOMP; o++) acc[o] = 0.0f;

    const float* mb = metadata + ((size_t)b * CMAP + (size_t)cs * CRANGE) * FHW + hw;
#pragma unroll 4
    for (int c = 0; c < CRANGE; c++) {
        float m = mb[c * FHW];
#pragma unroll
        for (int o = 0; o < CCOMP; o++) acc[o] += m * wcs[c][o];
    }

    float* outp = comp_ws + ((size_t)b * FHW + hw) * CCOMP;
    const float bs = (cs == 0) ? 1.0f : 0.0f;
#pragma unroll
    for (int o = 0; o < CCOMP; o++) {
        atomicAdd(&outp[o], acc[o] + bs * comp_b[o]);
    }
}

// K2: per-token: PE + LSTM + bilinear sample + vf + Q/K/V.  64-thread blocks,
// 256 blocks -> every CU gets work.
__global__ void k_token(const float* __restrict__ x,
                        const float* __restrict__ w_ih,
                        const float* __restrict__ b_ih,
                        const float* __restrict__ b_hh,
                        const float* __restrict__ fc_w,  const float* __restrict__ fc_b,
                        const float* __restrict__ fc2_w, const float* __restrict__ fc2_b,
                        const float* __restrict__ fc3_w, const float* __restrict__ fc3_b,
                        const float* __restrict__ vf_w,  const float* __restrict__ vf_b,
                        const float* __restrict__ comp_ws,
                        float* __restrict__ Qw, float* __restrict__ Kw, float* __restrict__ Vw) {
    const int m = blockIdx.x * 64 + threadIdx.x;
    const int b = m >> 13;          // / TN
    const int p = m & (TN - 1);
    const int t = p >> 7;           // / NN

    const float px = x[(size_t)(b * 2 + 0) * TN + p];
    const float py = x[(size_t)(b * 2 + 1) * TN + p];

    // positional encoding (c=2 -> div=1): (sin t, cos t)
    const float xr0 = px + __sinf((float)t);
    const float xr1 = py + __cosf((float)t);

    // single-step LSTM, h0=c0=0: gates = xr @ w_ih.T + b_ih + b_hh
    float X[4];
#pragma unroll
    for (int j = 0; j < 4; j++) {
        float gi = xr0 * w_ih[(j)      * 2] + xr1 * w_ih[(j)      * 2 + 1] + b_ih[j]      + b_hh[j];
        float gg = xr0 * w_ih[(8 + j)  * 2] + xr1 * w_ih[(8 + j)  * 2 + 1] + b_ih[8 + j]  + b_hh[8 + j];
        float go = xr0 * w_ih[(12 + j) * 2] + xr1 * w_ih[(12 + j) * 2 + 1] + b_ih[12 + j] + b_hh[12 + j];
        float cst = fast_sigmoid(gi) * fast_tanh(gg);
        X[j] = fast_sigmoid(go) * fast_tanh(cst);
    }

    // bilinear grid-sample of comp (zeros padding, align_corners=False)
    float lc[CCOMP];
#pragma unroll
    for (int c = 0; c < CCOMP; c++) lc[c] = 0.0f;

    const float ix = px * (1.0f / 32.0f) - 0.5f;
    const float iy = py * (1.0f / 32.0f) - 0.5f;
    const float fx0 = floorf(ix), fy0 = floorf(iy);
    const float wx = ix - fx0, wy = iy - fy0;
    const int x0 = (int)fx0, y0 = (int)fy0;
    const float* cb = comp_ws + (size_t)b * FHW * CCOMP;

#pragma unroll
    for (int dy = 0; dy < 2; dy++) {
#pragma unroll
        for (int dx = 0; dx < 2; dx++) {
            int xx = x0 + dx, yy = y0 + dy;
            if (xx < 0 || xx > 15 || yy < 0 || yy > 15) continue;
            float w = (dy ? wy : 1.0f - wy) * (dx ? wx : 1.0f - wx);
            const float* cp = cb + (yy * 16 + xx) * CCOMP;
#pragma unroll
            for (int c = 0; c < CCOMP; c++) lc[c] += w * cp[c];
        }
    }

    // vf: X2 = [X(4), lc(32)] @ vf_w.T + vf_b   (vf_w: [4,36])
    float X2[4];
#pragma unroll
    for (int j = 0; j < 4; j++) {
        float a = vf_b[j];
#pragma unroll
        for (int k = 0; k < 4; k++) a += X[k] * vf_w[j * 36 + k];
#pragma unroll
        for (int c = 0; c < CCOMP; c++) a += lc[c] * vf_w[j * 36 + 4 + c];
        X2[j] = a;
    }

    // Q from X2 (fc_w [8,4]); K,V from xr (fc2_w/fc3_w [8,2])
#pragma unroll
    for (int d = 0; d < 8; d++) {
        float q = fc_b[d];
#pragma unroll
        for (int k = 0; k < 4; k++) q += X2[k] * fc_w[d * 4 + k];
        Qw[(size_t)m * 8 + d] = q;
        Kw[(size_t)m * 8 + d] = fc2_b[d] + xr0 * fc2_w[d * 2] + xr1 * fc2_w[d * 2 + 1];
        Vw[(size_t)m * 8 + d] = fc3_b[d] + xr0 * fc3_w[d * 2] + xr1 * fc3_w[d * 2 + 1];
    }
}

// K3: out[q,:] += sum_{k in split} sigmoid(Q_q . K_k) * V_k
// grid (BB*16, KSPLIT=32) = 1024 blocks: each block = 512 q rows (2/thread),
// 256 k rows (2 LDS chunks of 128).
__global__ void __launch_bounds__(256, 4) k_attn(const float* __restrict__ Qw,
                                                 const float* __restrict__ Kw,
                                                 const float* __restrict__ Vw,
                                                 float* __restrict__ Ow) {
    __shared__ float sK[KC][8];
    __shared__ float sV[KC][8];

    const int tile = blockIdx.x;       // 0..31
    const int b  = tile >> 4;
    const int tq = tile & 15;
    const int ks = blockIdx.y;

    const int q0 = b * TN + tq * 512 + threadIdx.x;
    const int q1 = q0 + 256;

    float Q0[8], Q1[8], a0[8], a1[8];
#pragma unroll
    for (int d = 0; d < 8; d++) {
        Q0[d] = Qw[(size_t)q0 * 8 + d];
        Q1[d] = Qw[(size_t)q1 * 8 + d];
        a0[d] = 0.0f;
        a1[d] = 0.0f;
    }

    const int kbase = b * TN + ks * (TN / KSPLIT);
    for (int ch = 0; ch < TN / KSPLIT; ch += KC) {
        // cooperative stage of KC rows of K and V (KC*8 = 1024 floats each)
        ((float4*)&sK[0][0])[threadIdx.x] =
            ((const float4*)(Kw + (size_t)(kbase + ch) * 8))[threadIdx.x];
        ((float4*)&sV[0][0])[threadIdx.x] =
            ((const float4*)(Vw + (size_t)(kbase + ch) * 8))[threadIdx.x];
        __syncthreads();

#pragma unroll 2
        for (int j = 0; j < KC; j++) {
            const float4* kj = (const float4*)&sK[j][0];
            float4 ka = kj[0], kb = kj[1];
            float d0 = Q0[0] * ka.x + Q0[1] * ka.y + Q0[2] * ka.z + Q0[3] * ka.w
                     + Q0[4] * kb.x + Q0[5] * kb.y + Q0[6] * kb.z + Q0[7] * kb.w;
            float d1 = Q1[0] * ka.x + Q1[1] * ka.y + Q1[2] * ka.z + Q1[3] * ka.w
                     + Q1[4] * kb.x + Q1[5] * kb.y + Q1[6] * kb.z + Q1[7] * kb.w;
            float p0 = fast_sigmoid(d0);
            float p1 = fast_sigmoid(d1);
            const float4* vj = (const float4*)&sV[j][0];
            float4 va = vj[0], vb = vj[1];
            a0[0] += p0 * va.x; a0[1] += p0 * va.y; a0[2] += p0 * va.z; a0[3] += p0 * va.w;
            a0[4] += p0 * vb.x; a0[5] += p0 * vb.y; a0[6] += p0 * vb.z; a0[7] += p0 * vb.w;
            a1[0] += p1 * va.x; a1[1] += p1 * va.y; a1[2] += p1 * va.z; a1[3] += p1 * va.w;
            a1[4] += p1 * vb.x; a1[5] += p1 * vb.y; a1[6] += p1 * vb.z; a1[7] += p1 * vb.w;
        }
        __syncthreads();
    }

#pragma unroll
    for (int d = 0; d < 8; d++) {
        atomicAdd(&Ow[(size_t)q0 * 8 + d], a0[d]);
        atomicAdd(&Ow[(size_t)q1 * 8 + d], a1[d]);
    }
}

// K4: threshold-ReLU + fcout + transpose to [B,2,T,N]
__global__ void k_out(const float* __restrict__ Ow,
                      const float* __restrict__ fcout_w,
                      const float* __restrict__ fcout_b,
                      float* __restrict__ y) {
    const int m = blockIdx.x * 64 + threadIdx.x;
    const int b = m >> 13;
    const int p = m & (TN - 1);

    float f0 = fcout_b[0], f1 = fcout_b[1];
#pragma unroll
    for (int d = 0; d < 8; d++) {
        float v = Ow[(size_t)m * 8 + d];
        v = (v > 0.5f) ? v : 0.0f;
        f0 += v * fcout_w[d];
        f1 += v * fcout_w[8 + d];
    }
    y[(size_t)(b * 2 + 0) * TN + p] = f0;
    y[(size_t)(b * 2 + 1) * TN + p] = f1;
}

extern "C" void kernel_launch(void* const* d_in, const int* in_sizes, int n_in,
                              void* d_out, int out_size, void* d_ws, size_t ws_size,
                              hipStream_t stream) {
    const float* x        = (const float*)d_in[0];
    const float* metadata = (const float*)d_in[1];
    const float* w_ih     = (const float*)d_in[2];
    // d_in[3] = w_hh: unused (h0 = 0)
    const float* b_ih     = (const float*)d_in[4];
    const float* b_hh     = (const float*)d_in[5];
    const float* fc_w     = (const float*)d_in[6];
    const float* fc_b     = (const float*)d_in[7];
    const float* fc2_w    = (const float*)d_in[8];
    const float* fc2_b    = (const float*)d_in[9];
    const float* fc3_w    = (const float*)d_in[10];
    const float* fc3_b    = (const float*)d_in[11];
    const float* comp_w   = (const float*)d_in[12];
    const float* comp_b   = (const float*)d_in[13];
    const float* vf_w     = (const float*)d_in[14];
    const float* vf_b     = (const float*)d_in[15];
    const float* fcout_w  = (const float*)d_in[16];
    const float* fcout_b  = (const float*)d_in[17];

    float* ws      = (float*)d_ws;
    float* Ow      = ws + OFF_O;
    float* comp_ws = ws + OFF_COMP;
    float* Qw      = ws + OFF_Q;
    float* Kw      = ws + OFF_K;
    float* Vw      = ws + OFF_V;

    // zero the atomic accumulators (O and comp regions are contiguous)
    hipMemsetAsync(ws, 0, (size_t)(MM * 8 + BB * FHW * CCOMP) * sizeof(float), stream);

    k_comp<<<dim3(BB, CSPLIT), 256, 0, stream>>>(metadata, comp_w, comp_b, comp_ws);

    k_token<<<MM / 64, 64, 0, stream>>>(x, w_ih, b_ih, b_hh,
                                        fc_w, fc_b, fc2_w, fc2_b, fc3_w, fc3_b,
                                        vf_w, vf_b, comp_ws, Qw, Kw, Vw);

    k_attn<<<dim3(BB * 16, KSPLIT), 256, 0, stream>>>(Qw, Kw, Vw, Ow);

    k_out<<<MM / 64, 64, 0, stream>>>(Ow, fcout_w, fcout_b, (float*)d_out);
}

// Round 3
// 223.220 us; speedup vs baseline: 1.4072x; 1.2977x over previous
//
#include <hip/hip_runtime.h>
#include <math.h>

// Problem constants (from reference)
#define BB    2
#define TT    64
#define NN    128
#define TN    8192      // TT*NN
#define MM    16384     // BB*TN
#define CMAP  2048
#define CCOMP 32
#define FHW   256       // 16*16

// comp kernel split
#define CSPLIT 32
#define CRANGE 64       // CMAP / CSPLIT

// attention tiling
#define KC    128       // k rows staged in LDS per chunk
#define QPT   4         // q rows per thread
#define QTILE 1024      // 256 threads * QPT
#define NQT   16        // MM / QTILE  (8 per batch)

// workspace layout (float offsets) -- partial P buffer goes LAST (size varies)
#define OFF_CP    0                              // CSPLIT * BB*FHW*CCOMP = 524288
#define OFF_COMP  (OFF_CP + CSPLIT*BB*FHW*CCOMP) // BB*FHW*CCOMP = 16384
#define OFF_Q     (OFF_COMP + BB*FHW*CCOMP)      // MM*8
#define OFF_K     (OFF_Q + MM*8)
#define OFF_V     (OFF_K + MM*8)
#define OFF_P     (OFF_V + MM*8)                 // ksplit * MM*8

__device__ __forceinline__ float fast_sigmoid(float v) {
    return __builtin_amdgcn_rcpf(1.0f + __expf(-v));
}

__device__ __forceinline__ float fast_tanh(float v) {
    return 1.0f - 2.0f * __builtin_amdgcn_rcpf(1.0f + __expf(2.0f * v));
}

// K1a: comp partials (no atomics). Cp[cs][ (b*FHW+hw)*32 + o ]
__global__ void k_comp_p(const float* __restrict__ metadata,
                         const float* __restrict__ comp_w,
                         float* __restrict__ Cp) {
    const int b  = blockIdx.x;
    const int cs = blockIdx.y;
    const int hw = threadIdx.x;

    __shared__ float wcs[CRANGE][CCOMP];   // [c][o]
    for (int i = threadIdx.x; i < CRANGE * CCOMP; i += 256) {
        int c = i / CCOMP, o = i % CCOMP;
        wcs[c][o] = comp_w[o * CMAP + cs * CRANGE + c];
    }
    __syncthreads();

    float acc[CCOMP];
#pragma unroll
    for (int o = 0; o < CCOMP; o++) acc[o] = 0.0f;

    const float* mb = metadata + ((size_t)b * CMAP + (size_t)cs * CRANGE) * FHW + hw;
#pragma unroll 4
    for (int c = 0; c < CRANGE; c++) {
        float m = mb[c * FHW];
#pragma unroll
        for (int o = 0; o < CCOMP; o++) acc[o] += m * wcs[c][o];
    }

    float* outp = Cp + (size_t)cs * (BB * FHW * CCOMP) + ((size_t)b * FHW + hw) * CCOMP;
#pragma unroll
    for (int o = 0; o < CCOMP; o += 4) {
        *(float4*)&outp[o] = make_float4(acc[o], acc[o + 1], acc[o + 2], acc[o + 3]);
    }
}

// K1b: reduce CSPLIT partials + bias -> comp_ws  (16384 outputs)
__global__ void k_comp_reduce(const float* __restrict__ Cp,
                              const float* __restrict__ comp_b,
                              float* __restrict__ comp_ws) {
    const int i = blockIdx.x * 256 + threadIdx.x;   // 0..16383
    float s = comp_b[i & (CCOMP - 1)];
#pragma unroll
    for (int cs = 0; cs < CSPLIT; cs++) {
        s += Cp[(size_t)cs * (BB * FHW * CCOMP) + i];
    }
    comp_ws[i] = s;
}

// K2: per-token: PE + LSTM + bilinear sample + vf + Q/K/V
__global__ void k_token(const float* __restrict__ x,
                        const float* __restrict__ w_ih,
                        const float* __restrict__ b_ih,
                        const float* __restrict__ b_hh,
                        const float* __restrict__ fc_w,  const float* __restrict__ fc_b,
                        const float* __restrict__ fc2_w, const float* __restrict__ fc2_b,
                        const float* __restrict__ fc3_w, const float* __restrict__ fc3_b,
                        const float* __restrict__ vf_w,  const float* __restrict__ vf_b,
                        const float* __restrict__ comp_ws,
                        float* __restrict__ Qw, float* __restrict__ Kw, float* __restrict__ Vw) {
    const int m = blockIdx.x * 64 + threadIdx.x;
    const int b = m >> 13;          // / TN
    const int p = m & (TN - 1);
    const int t = p >> 7;           // / NN

    const float px = x[(size_t)(b * 2 + 0) * TN + p];
    const float py = x[(size_t)(b * 2 + 1) * TN + p];

    // positional encoding (c=2 -> div=1): (sin t, cos t)
    const float xr0 = px + __sinf((float)t);
    const float xr1 = py + __cosf((float)t);

    // single-step LSTM, h0=c0=0
    float X[4];
#pragma unroll
    for (int j = 0; j < 4; j++) {
        float gi = xr0 * w_ih[(j)      * 2] + xr1 * w_ih[(j)      * 2 + 1] + b_ih[j]      + b_hh[j];
        float gg = xr0 * w_ih[(8 + j)  * 2] + xr1 * w_ih[(8 + j)  * 2 + 1] + b_ih[8 + j]  + b_hh[8 + j];
        float go = xr0 * w_ih[(12 + j) * 2] + xr1 * w_ih[(12 + j) * 2 + 1] + b_ih[12 + j] + b_hh[12 + j];
        float cst = fast_sigmoid(gi) * fast_tanh(gg);
        X[j] = fast_sigmoid(go) * fast_tanh(cst);
    }

    // bilinear grid-sample of comp (zeros padding, align_corners=False)
    float lc[CCOMP];
#pragma unroll
    for (int c = 0; c < CCOMP; c++) lc[c] = 0.0f;

    const float ix = px * (1.0f / 32.0f) - 0.5f;
    const float iy = py * (1.0f / 32.0f) - 0.5f;
    const float fx0 = floorf(ix), fy0 = floorf(iy);
    const float wx = ix - fx0, wy = iy - fy0;
    const int x0 = (int)fx0, y0 = (int)fy0;
    const float* cb = comp_ws + (size_t)b * FHW * CCOMP;

#pragma unroll
    for (int dy = 0; dy < 2; dy++) {
#pragma unroll
        for (int dx = 0; dx < 2; dx++) {
            int xx = x0 + dx, yy = y0 + dy;
            if (xx < 0 || xx > 15 || yy < 0 || yy > 15) continue;
            float w = (dy ? wy : 1.0f - wy) * (dx ? wx : 1.0f - wx);
            const float* cp = cb + (yy * 16 + xx) * CCOMP;
#pragma unroll
            for (int c = 0; c < CCOMP; c++) lc[c] += w * cp[c];
        }
    }

    // vf: X2 = [X(4), lc(32)] @ vf_w.T + vf_b
    float X2[4];
#pragma unroll
    for (int j = 0; j < 4; j++) {
        float a = vf_b[j];
#pragma unroll
        for (int k = 0; k < 4; k++) a += X[k] * vf_w[j * 36 + k];
#pragma unroll
        for (int c = 0; c < CCOMP; c++) a += lc[c] * vf_w[j * 36 + 4 + c];
        X2[j] = a;
    }

#pragma unroll
    for (int d = 0; d < 8; d++) {
        float q = fc_b[d];
#pragma unroll
        for (int k = 0; k < 4; k++) q += X2[k] * fc_w[d * 4 + k];
        Qw[(size_t)m * 8 + d] = q;
        Kw[(size_t)m * 8 + d] = fc2_b[d] + xr0 * fc2_w[d * 2] + xr1 * fc2_w[d * 2 + 1];
        Vw[(size_t)m * 8 + d] = fc3_b[d] + xr0 * fc3_w[d * 2] + xr1 * fc3_w[d * 2 + 1];
    }
}

// K3: partial attention, NO atomics. grid (NQT, ksplit).
// Each block: 1024 q rows (4/thread), krange k rows (multiple of KC).
// Pw[ks][q][d] plain stores.
__global__ void __launch_bounds__(256) k_attn(const float* __restrict__ Qw,
                                              const float* __restrict__ Kw,
                                              const float* __restrict__ Vw,
                                              float* __restrict__ Pw,
                                              int krange) {
    __shared__ float sK[KC * 8];
    __shared__ float sV[KC * 8];

    const int tile = blockIdx.x;       // 0..15
    const int b  = tile >> 3;
    const int tq = tile & 7;
    const int ks = blockIdx.y;

    const int qb = b * TN + tq * QTILE + threadIdx.x;

    float Q[QPT][8], acc[QPT][8];
#pragma unroll
    for (int qi = 0; qi < QPT; qi++) {
        const float4* qp = (const float4*)(Qw + (size_t)(qb + qi * 256) * 8);
        float4 qa = qp[0], qc = qp[1];
        Q[qi][0] = qa.x; Q[qi][1] = qa.y; Q[qi][2] = qa.z; Q[qi][3] = qa.w;
        Q[qi][4] = qc.x; Q[qi][5] = qc.y; Q[qi][6] = qc.z; Q[qi][7] = qc.w;
#pragma unroll
        for (int d = 0; d < 8; d++) acc[qi][d] = 0.0f;
    }

    const int kbase = b * TN + ks * krange;
    for (int ch = 0; ch < krange; ch += KC) {
        ((float4*)sK)[threadIdx.x] =
            ((const float4*)(Kw + (size_t)(kbase + ch) * 8))[threadIdx.x];
        ((float4*)sV)[threadIdx.x] =
            ((const float4*)(Vw + (size_t)(kbase + ch) * 8))[threadIdx.x];
        __syncthreads();

        for (int j = 0; j < KC; j++) {
            const float4* kj = (const float4*)&sK[j * 8];
            float4 ka = kj[0], kb2 = kj[1];
            const float4* vj = (const float4*)&sV[j * 8];
            float4 va = vj[0], vb = vj[1];
#pragma unroll
            for (int qi = 0; qi < QPT; qi++) {
                // two partial chains for ILP
                float dlo = Q[qi][0] * ka.x  + Q[qi][1] * ka.y
                          + Q[qi][2] * ka.z  + Q[qi][3] * ka.w;
                float dhi = Q[qi][4] * kb2.x + Q[qi][5] * kb2.y
                          + Q[qi][6] * kb2.z + Q[qi][7] * kb2.w;
                float p = fast_sigmoid(dlo + dhi);
                acc[qi][0] += p * va.x; acc[qi][1] += p * va.y;
                acc[qi][2] += p * va.z; acc[qi][3] += p * va.w;
                acc[qi][4] += p * vb.x; acc[qi][5] += p * vb.y;
                acc[qi][6] += p * vb.z; acc[qi][7] += p * vb.w;
            }
        }
        __syncthreads();
    }

#pragma unroll
    for (int qi = 0; qi < QPT; qi++) {
        float* op = Pw + ((size_t)ks * MM + (qb + qi * 256)) * 8;
        *(float4*)&op[0] = make_float4(acc[qi][0], acc[qi][1], acc[qi][2], acc[qi][3]);
        *(float4*)&op[4] = make_float4(acc[qi][4], acc[qi][5], acc[qi][6], acc[qi][7]);
    }
}

// K4: reduce ksplit partials + threshold-ReLU + fcout + transpose to [B,2,T,N]
__global__ void k_out(const float* __restrict__ Pw,
                      const float* __restrict__ fcout_w,
                      const float* __restrict__ fcout_b,
                      float* __restrict__ y,
                      int ksplit) {
    const int m = blockIdx.x * 256 + threadIdx.x;
    const int b = m >> 13;
    const int p = m & (TN - 1);

    float o[8];
#pragma unroll
    for (int d = 0; d < 8; d++) o[d] = 0.0f;
    for (int ks = 0; ks < ksplit; ks++) {
        const float4* pp = (const float4*)(Pw + ((size_t)ks * MM + m) * 8);
        float4 pa = pp[0], pb = pp[1];
        o[0] += pa.x; o[1] += pa.y; o[2] += pa.z; o[3] += pa.w;
        o[4] += pb.x; o[5] += pb.y; o[6] += pb.z; o[7] += pb.w;
    }

    float f0 = fcout_b[0], f1 = fcout_b[1];
#pragma unroll
    for (int d = 0; d < 8; d++) {
        float v = (o[d] > 0.5f) ? o[d] : 0.0f;
        f0 += v * fcout_w[d];
        f1 += v * fcout_w[8 + d];
    }
    y[(size_t)(b * 2 + 0) * TN + p] = f0;
    y[(size_t)(b * 2 + 1) * TN + p] = f1;
}

extern "C" void kernel_launch(void* const* d_in, const int* in_sizes, int n_in,
                              void* d_out, int out_size, void* d_ws, size_t ws_size,
                              hipStream_t stream) {
    const float* x        = (const float*)d_in[0];
    const float* metadata = (const float*)d_in[1];
    const float* w_ih     = (const float*)d_in[2];
    // d_in[3] = w_hh: unused (h0 = 0)
    const float* b_ih     = (const float*)d_in[4];
    const float* b_hh     = (const float*)d_in[5];
    const float* fc_w     = (const float*)d_in[6];
    const float* fc_b     = (const float*)d_in[7];
    const float* fc2_w    = (const float*)d_in[8];
    const float* fc2_b    = (const float*)d_in[9];
    const float* fc3_w    = (const float*)d_in[10];
    const float* fc3_b    = (const float*)d_in[11];
    const float* comp_w   = (const float*)d_in[12];
    const float* comp_b   = (const float*)d_in[13];
    const float* vf_w     = (const float*)d_in[14];
    const float* vf_b     = (const float*)d_in[15];
    const float* fcout_w  = (const float*)d_in[16];
    const float* fcout_b  = (const float*)d_in[17];

    float* ws      = (float*)d_ws;
    float* Cp      = ws + OFF_CP;
    float* comp_ws = ws + OFF_COMP;
    float* Qw      = ws + OFF_Q;
    float* Kw      = ws + OFF_K;
    float* Vw      = ws + OFF_V;
    float* Pw      = ws + OFF_P;

    // pick ksplit by available workspace: 64 -> 4 blocks/CU, else 32
    int ksplit = 32;
    {
        size_t need64 = ((size_t)OFF_P + (size_t)64 * MM * 8) * sizeof(float);
        if (ws_size >= need64) ksplit = 64;
    }
    const int krange = TN / ksplit;   // 128 or 256 (multiples of KC)

    k_comp_p<<<dim3(BB, CSPLIT), 256, 0, stream>>>(metadata, comp_w, Cp);

    k_comp_reduce<<<(BB * FHW * CCOMP) / 256, 256, 0, stream>>>(Cp, comp_b, comp_ws);

    k_token<<<MM / 64, 64, 0, stream>>>(x, w_ih, b_ih, b_hh,
                                        fc_w, fc_b, fc2_w, fc2_b, fc3_w, fc3_b,
                                        vf_w, vf_b, comp_ws, Qw, Kw, Vw);

    k_attn<<<dim3(NQT, ksplit), 256, 0, stream>>>(Qw, Kw, Vw, Pw, krange);

    k_out<<<MM / 256, 256, 0, stream>>>(Pw, fcout_w, fcout_b, (float*)d_out, ksplit);
}

// Round 4
// 165.659 us; speedup vs baseline: 1.8962x; 1.3475x over previous
//
#include <hip/hip_runtime.h>
#include <math.h>

// Problem constants (from reference)
#define BB    2
#define TT    64
#define NN    128
#define TN    8192      // TT*NN
#define MM    16384     // BB*TN
#define CMAP  2048
#define CCOMP 32
#define FHW   256       // 16*16

// comp kernel split
#define CSPLIT 128
#define CRANGE 16       // CMAP / CSPLIT

// attention tiling (rank-3 formulation)
#define QPT    4        // q rows per thread
#define QTILE  1024     // 256 threads * QPT
#define NQT    16       // MM / QTILE (8 per batch)
#define KSPLIT 64
#define KRANGE 128      // TN / KSPLIT

#define NEG_LOG2E (-1.44269504088896340736f)

// workspace layout (float offsets)
#define OFF_CP    0                                  // CSPLIT*BB*FHW*CCOMP = 2097152
#define OFF_COMP  (OFF_CP + CSPLIT*BB*FHW*CCOMP)     // 16384
#define OFF_A     (OFF_COMP + BB*FHW*CCOMP)          // MM*4  (alpha',beta',gamma',pad)
#define OFF_X     (OFF_A + MM*4)                     // MM*2  (xr0,xr1)
#define OFF_P     (OFF_X + MM*2)                     // KSPLIT*MM*4 (S0,S1,S2,pad)
// total = 6,406,144 floats = 25.6 MB

__device__ __forceinline__ float fast_sigmoid(float v) {
    return __builtin_amdgcn_rcpf(1.0f + __expf(-v));
}
__device__ __forceinline__ float fast_tanh(float v) {
    return 1.0f - 2.0f * __builtin_amdgcn_rcpf(1.0f + __expf(2.0f * v));
}

// K1a: comp partials (no atomics). Cp[cs][(b*FHW+hw)*32+o]
__global__ void k_comp_p(const float* __restrict__ metadata,
                         const float* __restrict__ comp_w,
                         float* __restrict__ Cp) {
    const int b  = blockIdx.x;
    const int cs = blockIdx.y;
    const int hw = threadIdx.x;

    __shared__ float wcs[CRANGE][CCOMP];   // [c][o], 2 KB
    for (int i = threadIdx.x; i < CRANGE * CCOMP; i += 256) {
        int c = i / CCOMP, o = i % CCOMP;
        wcs[c][o] = comp_w[o * CMAP + cs * CRANGE + c];
    }
    __syncthreads();

    float acc[CCOMP];
#pragma unroll
    for (int o = 0; o < CCOMP; o++) acc[o] = 0.0f;

    const float* mb = metadata + ((size_t)b * CMAP + (size_t)cs * CRANGE) * FHW + hw;
#pragma unroll
    for (int c = 0; c < CRANGE; c++) {
        float m = mb[c * FHW];
#pragma unroll
        for (int o = 0; o < CCOMP; o++) acc[o] += m * wcs[c][o];
    }

    float* outp = Cp + (size_t)cs * (BB * FHW * CCOMP) + ((size_t)b * FHW + hw) * CCOMP;
#pragma unroll
    for (int o = 0; o < CCOMP; o += 4) {
        *(float4*)&outp[o] = make_float4(acc[o], acc[o + 1], acc[o + 2], acc[o + 3]);
    }
}

// K1b: reduce CSPLIT partials + bias -> comp_ws (16384 outputs)
__global__ void k_comp_reduce(const float* __restrict__ Cp,
                              const float* __restrict__ comp_b,
                              float* __restrict__ comp_ws) {
    const int i = blockIdx.x * 256 + threadIdx.x;
    float s = comp_b[i & (CCOMP - 1)];
#pragma unroll 8
    for (int cs = 0; cs < CSPLIT; cs++) {
        s += Cp[(size_t)cs * (BB * FHW * CCOMP) + i];
    }
    comp_ws[i] = s;
}

// K2: per-token: PE + LSTM + bilinear sample + vf + Q -> (alpha,beta,gamma); xr
__global__ void k_token(const float* __restrict__ x,
                        const float* __restrict__ w_ih,
                        const float* __restrict__ b_ih,
                        const float* __restrict__ b_hh,
                        const float* __restrict__ fc_w,  const float* __restrict__ fc_b,
                        const float* __restrict__ fc2_w, const float* __restrict__ fc2_b,
                        const float* __restrict__ vf_w,  const float* __restrict__ vf_b,
                        const float* __restrict__ comp_ws,
                        float4* __restrict__ Aq, float2* __restrict__ Xr) {
    const int m = blockIdx.x * 64 + threadIdx.x;
    const int b = m >> 13;
    const int p = m & (TN - 1);
    const int t = p >> 7;

    const float px = x[(size_t)(b * 2 + 0) * TN + p];
    const float py = x[(size_t)(b * 2 + 1) * TN + p];

    const float xr0 = px + __sinf((float)t);
    const float xr1 = py + __cosf((float)t);
    Xr[m] = make_float2(xr0, xr1);

    // single-step LSTM, h0=c0=0
    float X[4];
#pragma unroll
    for (int j = 0; j < 4; j++) {
        float gi = xr0 * w_ih[(j)      * 2] + xr1 * w_ih[(j)      * 2 + 1] + b_ih[j]      + b_hh[j];
        float gg = xr0 * w_ih[(8 + j)  * 2] + xr1 * w_ih[(8 + j)  * 2 + 1] + b_ih[8 + j]  + b_hh[8 + j];
        float go = xr0 * w_ih[(12 + j) * 2] + xr1 * w_ih[(12 + j) * 2 + 1] + b_ih[12 + j] + b_hh[12 + j];
        float cst = fast_sigmoid(gi) * fast_tanh(gg);
        X[j] = fast_sigmoid(go) * fast_tanh(cst);
    }

    // bilinear grid-sample of comp (zeros padding, align_corners=False)
    float lc[CCOMP];
#pragma unroll
    for (int c = 0; c < CCOMP; c++) lc[c] = 0.0f;

    const float ix = px * (1.0f / 32.0f) - 0.5f;
    const float iy = py * (1.0f / 32.0f) - 0.5f;
    const float fx0 = floorf(ix), fy0 = floorf(iy);
    const float wx = ix - fx0, wy = iy - fy0;
    const int x0 = (int)fx0, y0 = (int)fy0;
    const float* cb = comp_ws + (size_t)b * FHW * CCOMP;

#pragma unroll
    for (int dy = 0; dy < 2; dy++) {
#pragma unroll
        for (int dx = 0; dx < 2; dx++) {
            int xx = x0 + dx, yy = y0 + dy;
            if (xx < 0 || xx > 15 || yy < 0 || yy > 15) continue;
            float w = (dy ? wy : 1.0f - wy) * (dx ? wx : 1.0f - wx);
            const float* cp = cb + (yy * 16 + xx) * CCOMP;
#pragma unroll
            for (int c = 0; c < CCOMP; c++) lc[c] += w * cp[c];
        }
    }

    // vf
    float X2[4];
#pragma unroll
    for (int j = 0; j < 4; j++) {
        float a = vf_b[j];
#pragma unroll
        for (int k = 0; k < 4; k++) a += X[k] * vf_w[j * 36 + k];
#pragma unroll
        for (int c = 0; c < CCOMP; c++) a += lc[c] * vf_w[j * 36 + 4 + c];
        X2[j] = a;
    }

    // Q then rank-3 projection onto K's affine basis:
    // alpha = Q.fc2_b, beta = Q.fc2_w[:,0], gamma = Q.fc2_w[:,1]
    float al = 0.0f, be = 0.0f, ga = 0.0f;
#pragma unroll
    for (int d = 0; d < 8; d++) {
        float q = fc_b[d];
#pragma unroll
        for (int k = 0; k < 4; k++) q += X2[k] * fc_w[d * 4 + k];
        al += q * fc2_b[d];
        be += q * fc2_w[d * 2];
        ga += q * fc2_w[d * 2 + 1];
    }
    // fold -log2e so attn uses exp2 directly
    Aq[m] = make_float4(NEG_LOG2E * al, NEG_LOG2E * be, NEG_LOG2E * ga, 0.0f);
}

// K3: rank-3 partial attention. grid (NQT, KSPLIT) = 1024 blocks.
// Per thread: 4 q rows; per block: 128 k rows staged once in LDS.
// Accumulates S0 = sum p, S1 = sum p*xr0, S2 = sum p*xr1.
__global__ void __launch_bounds__(256) k_attn(const float4* __restrict__ Aq,
                                              const float2* __restrict__ Xr,
                                              float4* __restrict__ Pw) {
    __shared__ float2 sX[KRANGE];    // 1 KB

    const int tile = blockIdx.x;     // 0..15
    const int b  = tile >> 3;
    const int tq = tile & 7;
    const int ks = blockIdx.y;

    const int qb = b * TN + tq * QTILE + threadIdx.x;

    float4 A[QPT];
    float S0[QPT], S1[QPT], S2[QPT];
#pragma unroll
    for (int qi = 0; qi < QPT; qi++) {
        A[qi] = Aq[qb + qi * 256];
        S0[qi] = 0.0f; S1[qi] = 0.0f; S2[qi] = 0.0f;
    }

    if (threadIdx.x < KRANGE) {
        sX[threadIdx.x] = Xr[b * TN + ks * KRANGE + threadIdx.x];
    }
    __syncthreads();

#pragma unroll 4
    for (int j = 0; j < KRANGE; j++) {
        const float2 xv = sX[j];
#pragma unroll
        for (int qi = 0; qi < QPT; qi++) {
            float e = __builtin_amdgcn_exp2f(A[qi].x + A[qi].y * xv.x + A[qi].z * xv.y);
            float pr = __builtin_amdgcn_rcpf(1.0f + e);
            S0[qi] += pr;
            S1[qi] += pr * xv.x;
            S2[qi] += pr * xv.y;
        }
    }

#pragma unroll
    for (int qi = 0; qi < QPT; qi++) {
        Pw[(size_t)ks * MM + (qb + qi * 256)] = make_float4(S0[qi], S1[qi], S2[qi], 0.0f);
    }
}

// K4: reduce KSPLIT partials, reconstruct out8 from V's affine basis,
// threshold-ReLU + fcout + transpose to [B,2,T,N]
__global__ void k_out(const float4* __restrict__ Pw,
                      const float* __restrict__ fc3_w, const float* __restrict__ fc3_b,
                      const float* __restrict__ fcout_w,
                      const float* __restrict__ fcout_b,
                      float* __restrict__ y) {
    const int m = blockIdx.x * 64 + threadIdx.x;
    const int b = m >> 13;
    const int p = m & (TN - 1);

    float S0 = 0.0f, S1 = 0.0f, S2 = 0.0f;
#pragma unroll 8
    for (int ks = 0; ks < KSPLIT; ks++) {
        float4 pp = Pw[(size_t)ks * MM + m];
        S0 += pp.x; S1 += pp.y; S2 += pp.z;
    }

    float f0 = fcout_b[0], f1 = fcout_b[1];
#pragma unroll
    for (int d = 0; d < 8; d++) {
        float v = S0 * fc3_b[d] + S1 * fc3_w[d * 2] + S2 * fc3_w[d * 2 + 1];
        v = (v > 0.5f) ? v : 0.0f;
        f0 += v * fcout_w[d];
        f1 += v * fcout_w[8 + d];
    }
    y[(size_t)(b * 2 + 0) * TN + p] = f0;
    y[(size_t)(b * 2 + 1) * TN + p] = f1;
}

extern "C" void kernel_launch(void* const* d_in, const int* in_sizes, int n_in,
                              void* d_out, int out_size, void* d_ws, size_t ws_size,
                              hipStream_t stream) {
    const float* x        = (const float*)d_in[0];
    const float* metadata = (const float*)d_in[1];
    const float* w_ih     = (const float*)d_in[2];
    // d_in[3] = w_hh: unused (h0 = 0)
    const float* b_ih     = (const float*)d_in[4];
    const float* b_hh     = (const float*)d_in[5];
    const float* fc_w     = (const float*)d_in[6];
    const float* fc_b     = (const float*)d_in[7];
    const float* fc2_w    = (const float*)d_in[8];
    const float* fc2_b    = (const float*)d_in[9];
    const float* fc3_w    = (const float*)d_in[10];
    const float* fc3_b    = (const float*)d_in[11];
    const float* comp_w   = (const float*)d_in[12];
    const float* comp_b   = (const float*)d_in[13];
    const float* vf_w     = (const float*)d_in[14];
    const float* vf_b     = (const float*)d_in[15];
    const float* fcout_w  = (const float*)d_in[16];
    const float* fcout_b  = (const float*)d_in[17];

    float*  ws      = (float*)d_ws;
    float*  Cp      = ws + OFF_CP;
    float*  comp_ws = ws + OFF_COMP;
    float4* Aq      = (float4*)(ws + OFF_A);
    float2* Xr      = (float2*)(ws + OFF_X);
    float4* Pw      = (float4*)(ws + OFF_P);

    k_comp_p<<<dim3(BB, CSPLIT), 256, 0, stream>>>(metadata, comp_w, Cp);

    k_comp_reduce<<<(BB * FHW * CCOMP) / 256, 256, 0, stream>>>(Cp, comp_b, comp_ws);

    k_token<<<MM / 64, 64, 0, stream>>>(x, w_ih, b_ih, b_hh,
                                        fc_w, fc_b, fc2_w, fc2_b,
                                        vf_w, vf_b, comp_ws, Aq, Xr);

    k_attn<<<dim3(NQT, KSPLIT), 256, 0, stream>>>(Aq, Xr, Pw);

    k_out<<<MM / 64, 64, 0, stream>>>(Pw, fc3_w, fc3_b, fcout_w, fcout_b, (float*)d_out);
}

// Round 5
// 156.729 us; speedup vs baseline: 2.0042x; 1.0570x over previous
//
#include <hip/hip_runtime.h>
#include <math.h>

// Problem constants (from reference)
#define BB    2
#define TT    64
#define NN    128
#define TN    8192      // TT*NN
#define MM    16384     // BB*TN
#define CMAP  2048
#define CCOMP 32
#define FHW   256       // 16*16

// comp kernel split
#define CSPLIT 64
#define CRANGE 32       // CMAP / CSPLIT

// attention tiling (rank-3 formulation, single LDS stage)
#define QPT    4        // q rows per thread
#define QTILE  1024     // 256 threads * QPT
#define NQT    16       // MM / QTILE (8 per batch)
#define KSPLIT 32
#define KRANGE 256      // TN / KSPLIT  == block size (one float2 per thread)

#define NEG_LOG2E (-1.44269504088896340736f)

// workspace layout (float offsets)
#define OFF_CP    0                                  // CSPLIT*BB*FHW*CCOMP = 1048576
#define OFF_COMP  (OFF_CP + CSPLIT*BB*FHW*CCOMP)     // 16384
#define OFF_A     (OFF_COMP + BB*FHW*CCOMP)          // MM*4  (alpha',beta',gamma',pad)
#define OFF_X     (OFF_A + MM*4)                     // MM*2  (xr0,xr1)
#define OFF_P     (OFF_X + MM*2)                     // KSPLIT*MM*4 (S0,S1,S2,pad)
// total ~ 3.26M floats = 13 MB

__device__ __forceinline__ float fast_sigmoid(float v) {
    return __builtin_amdgcn_rcpf(1.0f + __expf(-v));
}
__device__ __forceinline__ float fast_tanh(float v) {
    return 1.0f - 2.0f * __builtin_amdgcn_rcpf(1.0f + __expf(2.0f * v));
}

// K1a: comp partials (no atomics). Cp[cs][(b*FHW+hw)*32+o]
__global__ void k_comp_p(const float* __restrict__ metadata,
                         const float* __restrict__ comp_w,
                         float* __restrict__ Cp) {
    const int b  = blockIdx.x;
    const int cs = blockIdx.y;
    const int hw = threadIdx.x;

    __shared__ float wcs[CRANGE][CCOMP];   // [c][o], 4 KB
    for (int i = threadIdx.x; i < CRANGE * CCOMP; i += 256) {
        int c = i / CCOMP, o = i % CCOMP;
        wcs[c][o] = comp_w[o * CMAP + cs * CRANGE + c];
    }
    __syncthreads();

    float acc[CCOMP];
#pragma unroll
    for (int o = 0; o < CCOMP; o++) acc[o] = 0.0f;

    const float* mb = metadata + ((size_t)b * CMAP + (size_t)cs * CRANGE) * FHW + hw;
#pragma unroll 4
    for (int c = 0; c < CRANGE; c++) {
        float m = mb[c * FHW];
#pragma unroll
        for (int o = 0; o < CCOMP; o++) acc[o] += m * wcs[c][o];
    }

    float* outp = Cp + (size_t)cs * (BB * FHW * CCOMP) + ((size_t)b * FHW + hw) * CCOMP;
#pragma unroll
    for (int o = 0; o < CCOMP; o += 4) {
        *(float4*)&outp[o] = make_float4(acc[o], acc[o + 1], acc[o + 2], acc[o + 3]);
    }
}

// K1b: reduce CSPLIT partials + bias -> comp_ws. 4 threads per output.
// grid 256 blocks x 256 thr: i = blk*64 + t/4, lane r=t%4 sums 16 partials.
__global__ void k_comp_reduce(const float* __restrict__ Cp,
                              const float* __restrict__ comp_b,
                              float* __restrict__ comp_ws) {
    const int t = threadIdx.x;
    const int i = blockIdx.x * 64 + (t >> 2);
    const int r = t & 3;

    float s = 0.0f;
#pragma unroll
    for (int k = 0; k < CSPLIT / 4; k++) {
        s += Cp[(size_t)(r * (CSPLIT / 4) + k) * (BB * FHW * CCOMP) + i];
    }
    s += __shfl_xor(s, 1);
    s += __shfl_xor(s, 2);
    if (r == 0) comp_ws[i] = s + comp_b[i & (CCOMP - 1)];
}

// K2: per-token: PE + LSTM + bilinear sample + vf + Q -> (alpha,beta,gamma); xr
__global__ void k_token(const float* __restrict__ x,
                        const float* __restrict__ w_ih,
                        const float* __restrict__ b_ih,
                        const float* __restrict__ b_hh,
                        const float* __restrict__ fc_w,  const float* __restrict__ fc_b,
                        const float* __restrict__ fc2_w, const float* __restrict__ fc2_b,
                        const float* __restrict__ vf_w,  const float* __restrict__ vf_b,
                        const float* __restrict__ comp_ws,
                        float4* __restrict__ Aq, float2* __restrict__ Xr) {
    const int m = blockIdx.x * 64 + threadIdx.x;
    const int b = m >> 13;
    const int p = m & (TN - 1);
    const int t = p >> 7;

    const float px = x[(size_t)(b * 2 + 0) * TN + p];
    const float py = x[(size_t)(b * 2 + 1) * TN + p];

    const float xr0 = px + __sinf((float)t);
    const float xr1 = py + __cosf((float)t);
    Xr[m] = make_float2(xr0, xr1);

    // single-step LSTM, h0=c0=0
    float X[4];
#pragma unroll
    for (int j = 0; j < 4; j++) {
        float gi = xr0 * w_ih[(j)      * 2] + xr1 * w_ih[(j)      * 2 + 1] + b_ih[j]      + b_hh[j];
        float gg = xr0 * w_ih[(8 + j)  * 2] + xr1 * w_ih[(8 + j)  * 2 + 1] + b_ih[8 + j]  + b_hh[8 + j];
        float go = xr0 * w_ih[(12 + j) * 2] + xr1 * w_ih[(12 + j) * 2 + 1] + b_ih[12 + j] + b_hh[12 + j];
        float cst = fast_sigmoid(gi) * fast_tanh(gg);
        X[j] = fast_sigmoid(go) * fast_tanh(cst);
    }

    // bilinear grid-sample of comp (zeros padding, align_corners=False)
    float lc[CCOMP];
#pragma unroll
    for (int c = 0; c < CCOMP; c++) lc[c] = 0.0f;

    const float ix = px * (1.0f / 32.0f) - 0.5f;
    const float iy = py * (1.0f / 32.0f) - 0.5f;
    const float fx0 = floorf(ix), fy0 = floorf(iy);
    const float wx = ix - fx0, wy = iy - fy0;
    const int x0 = (int)fx0, y0 = (int)fy0;
    const float* cb = comp_ws + (size_t)b * FHW * CCOMP;

#pragma unroll
    for (int dy = 0; dy < 2; dy++) {
#pragma unroll
        for (int dx = 0; dx < 2; dx++) {
            int xx = x0 + dx, yy = y0 + dy;
            if (xx < 0 || xx > 15 || yy < 0 || yy > 15) continue;
            float w = (dy ? wy : 1.0f - wy) * (dx ? wx : 1.0f - wx);
            const float4* cp4 = (const float4*)(cb + (yy * 16 + xx) * CCOMP);
#pragma unroll
            for (int c4 = 0; c4 < CCOMP / 4; c4++) {
                float4 v = cp4[c4];
                lc[c4 * 4 + 0] += w * v.x;
                lc[c4 * 4 + 1] += w * v.y;
                lc[c4 * 4 + 2] += w * v.z;
                lc[c4 * 4 + 3] += w * v.w;
            }
        }
    }

    // vf
    float X2[4];
#pragma unroll
    for (int j = 0; j < 4; j++) {
        float a = vf_b[j];
#pragma unroll
        for (int k = 0; k < 4; k++) a += X[k] * vf_w[j * 36 + k];
#pragma unroll
        for (int c = 0; c < CCOMP; c++) a += lc[c] * vf_w[j * 36 + 4 + c];
        X2[j] = a;
    }

    // Q then rank-3 projection onto K's affine basis
    float al = 0.0f, be = 0.0f, ga = 0.0f;
#pragma unroll
    for (int d = 0; d < 8; d++) {
        float q = fc_b[d];
#pragma unroll
        for (int k = 0; k < 4; k++) q += X2[k] * fc_w[d * 4 + k];
        al += q * fc2_b[d];
        be += q * fc2_w[d * 2];
        ga += q * fc2_w[d * 2 + 1];
    }
    Aq[m] = make_float4(NEG_LOG2E * al, NEG_LOG2E * be, NEG_LOG2E * ga, 0.0f);
}

// K3: rank-3 partial attention, single LDS stage. grid (NQT, KSPLIT) = 512.
// Per thread: 4 q rows x 256 k rows. S0=sum p, S1=sum p*x0, S2=sum p*x1.
__global__ void __launch_bounds__(256) k_attn(const float4* __restrict__ Aq,
                                              const float2* __restrict__ Xr,
                                              float4* __restrict__ Pw) {
    __shared__ float2 sX[KRANGE];    // 2 KB, one float2 per thread

    const int tile = blockIdx.x;     // 0..15
    const int b  = tile >> 3;
    const int tq = tile & 7;
    const int ks = blockIdx.y;

    const int qb = b * TN + tq * QTILE + threadIdx.x;

    float4 A[QPT];
    float S0[QPT], S1[QPT], S2[QPT];
#pragma unroll
    for (int qi = 0; qi < QPT; qi++) {
        A[qi] = Aq[qb + qi * 256];
        S0[qi] = 0.0f; S1[qi] = 0.0f; S2[qi] = 0.0f;
    }

    sX[threadIdx.x] = Xr[b * TN + ks * KRANGE + threadIdx.x];
    __syncthreads();

#pragma unroll 8
    for (int j = 0; j < KRANGE; j++) {
        const float2 xv = sX[j];
#pragma unroll
        for (int qi = 0; qi < QPT; qi++) {
            float e = __builtin_amdgcn_exp2f(A[qi].x + A[qi].y * xv.x + A[qi].z * xv.y);
            float pr = __builtin_amdgcn_rcpf(1.0f + e);
            S0[qi] += pr;
            S1[qi] += pr * xv.x;
            S2[qi] += pr * xv.y;
        }
    }

#pragma unroll
    for (int qi = 0; qi < QPT; qi++) {
        Pw[(size_t)ks * MM + (qb + qi * 256)] = make_float4(S0[qi], S1[qi], S2[qi], 0.0f);
    }
}

// K4: reduce KSPLIT partials (4 threads/token), reconstruct via V's affine
// basis, threshold-ReLU + fcout + transpose. grid 256 blocks x 256 thr.
__global__ void k_out(const float4* __restrict__ Pw,
                      const float* __restrict__ fc3_w, const float* __restrict__ fc3_b,
                      const float* __restrict__ fcout_w,
                      const float* __restrict__ fcout_b,
                      float* __restrict__ y) {
    const int t = threadIdx.x;
    const int m = blockIdx.x * 64 + (t >> 2);
    const int r = t & 3;
    const int b = m >> 13;
    const int p = m & (TN - 1);

    float S0 = 0.0f, S1 = 0.0f, S2 = 0.0f;
#pragma unroll
    for (int k = 0; k < KSPLIT / 4; k++) {
        float4 pp = Pw[(size_t)(r * (KSPLIT / 4) + k) * MM + m];
        S0 += pp.x; S1 += pp.y; S2 += pp.z;
    }
    S0 += __shfl_xor(S0, 1); S0 += __shfl_xor(S0, 2);
    S1 += __shfl_xor(S1, 1); S1 += __shfl_xor(S1, 2);
    S2 += __shfl_xor(S2, 1); S2 += __shfl_xor(S2, 2);

    if (r == 0) {
        float f0 = fcout_b[0], f1 = fcout_b[1];
#pragma unroll
        for (int d = 0; d < 8; d++) {
            float v = S0 * fc3_b[d] + S1 * fc3_w[d * 2] + S2 * fc3_w[d * 2 + 1];
            v = (v > 0.5f) ? v : 0.0f;
            f0 += v * fcout_w[d];
            f1 += v * fcout_w[8 + d];
        }
        y[(size_t)(b * 2 + 0) * TN + p] = f0;
        y[(size_t)(b * 2 + 1) * TN + p] = f1;
    }
}

extern "C" void kernel_launch(void* const* d_in, const int* in_sizes, int n_in,
                              void* d_out, int out_size, void* d_ws, size_t ws_size,
                              hipStream_t stream) {
    const float* x        = (const float*)d_in[0];
    const float* metadata = (const float*)d_in[1];
    const float* w_ih     = (const float*)d_in[2];
    // d_in[3] = w_hh: unused (h0 = 0)
    const float* b_ih     = (const float*)d_in[4];
    const float* b_hh     = (const float*)d_in[5];
    const float* fc_w     = (const float*)d_in[6];
    const float* fc_b     = (const float*)d_in[7];
    const float* fc2_w    = (const float*)d_in[8];
    const float* fc2_b    = (const float*)d_in[9];
    const float* fc3_w    = (const float*)d_in[10];
    const float* fc3_b    = (const float*)d_in[11];
    const float* comp_w   = (const float*)d_in[12];
    const float* comp_b   = (const float*)d_in[13];
    const float* vf_w     = (const float*)d_in[14];
    const float* vf_b     = (const float*)d_in[15];
    const float* fcout_w  = (const float*)d_in[16];
    const float* fcout_b  = (const float*)d_in[17];

    float*  ws      = (float*)d_ws;
    float*  Cp      = ws + OFF_CP;
    float*  comp_ws = ws + OFF_COMP;
    float4* Aq      = (float4*)(ws + OFF_A);
    float2* Xr      = (float2*)(ws + OFF_X);
    float4* Pw      = (float4*)(ws + OFF_P);

    k_comp_p<<<dim3(BB, CSPLIT), 256, 0, stream>>>(metadata, comp_w, Cp);

    k_comp_reduce<<<256, 256, 0, stream>>>(Cp, comp_b, comp_ws);

    k_token<<<MM / 64, 64, 0, stream>>>(x, w_ih, b_ih, b_hh,
                                        fc_w, fc_b, fc2_w, fc2_b,
                                        vf_w, vf_b, comp_ws, Aq, Xr);

    k_attn<<<dim3(NQT, KSPLIT), 256, 0, stream>>>(Aq, Xr, Pw);

    k_out<<<256, 256, 0, stream>>>(Pw, fc3_w, fc3_b, fcout_w, fcout_b, (float*)d_out);
}